// Round 4
// baseline (255.567 us; speedup 1.0000x reference)
//
#include <hip/hip_runtime.h>
#include <algorithm>
#include <cstdint>

// PRNG variant for replicating jax.random.uniform(jax.random.key(42), (1381,)):
//   0: partitionable threefry, keep HIGH 32 bits (o0)      [R1: FAILED]
//   1: partitionable threefry, keep LOW 32 bits (o1)       [R2: FAILED]
//   2: original (non-partitionable) split-counter threefry [fallback]
//   5: partitionable threefry, 32-bit combine = o0 ^ o1    [this round — matches
//      jax/_src/prng.py _threefry_random_bits_partitionable bit_width==32 path]
#ifndef PRNG_VARIANT
#define PRNG_VARIANT 5
#endif

constexpr int W_ = 690;
constexpr int NSEG_ = 2 * W_ + 1;   // 1381 segments
constexpr int NCUTS_ = 2 * W_ + 2;  // 1382 cut points

struct PermArg { unsigned short p[NSEG_]; }; // 2762 B kernarg, values < 1381

// ---------------- host-side threefry2x32 (exact JAX semantics) ----------------
static inline uint32_t rotl32_(uint32_t x, int d) { return (x << d) | (x >> (32 - d)); }

static void tf2x32(uint32_t k0, uint32_t k1, uint32_t x0, uint32_t x1,
                   uint32_t& o0, uint32_t& o1) {
  // ks = [k0, k1, k0^k1^0x1BD11BDA]; 20 rounds, rot sets alternate per group of 4
  const uint32_t ks2 = k0 ^ k1 ^ 0x1BD11BDAu;
  x0 += k0; x1 += k1;
  const int RA[4] = {13, 15, 26, 6}, RB[4] = {17, 29, 16, 24};
#define FOUR_(R) for (int i_ = 0; i_ < 4; ++i_) { x0 += x1; x1 = rotl32_(x1, R[i_]); x1 ^= x0; }
  FOUR_(RA) x0 += k1;  x1 += ks2 + 1u;
  FOUR_(RB) x0 += ks2; x1 += k0 + 2u;
  FOUR_(RA) x0 += k0;  x1 += k1 + 3u;
  FOUR_(RB) x0 += k1;  x1 += ks2 + 4u;
  FOUR_(RA) x0 += ks2; x1 += k0 + 5u;
#undef FOUR_
  o0 = x0; o1 = x1;
}

// perm = argsort(uniform(key(42), (1381,))) — pure function of constants.
static void compute_perm(unsigned short* perm) {
  uint32_t uk[NSEG_]; // top-23-bit keys; uniform value is monotone in this
#if PRNG_VARIANT == 2
  // original path: counts=iota(1381) padded to 1382, split halves as (x0,x1)
  uint32_t bits[NSEG_ + 1];
  for (int j = 0; j < 691; ++j) {
    uint32_t o0, o1;
    uint32_t x1 = (j < 690) ? (uint32_t)(691 + j) : 0u;
    tf2x32(0u, 42u, (uint32_t)j, x1, o0, o1);
    bits[j] = o0;
    if (j < 690) bits[691 + j] = o1;
  }
  for (int i = 0; i < NSEG_; ++i) uk[i] = bits[i] >> 9;
#else
  for (int i = 0; i < NSEG_; ++i) {
    uint32_t o0, o1;
    tf2x32(0u, 42u, 0u, (uint32_t)i, o0, o1); // u64 count i: hi=0 -> x0, lo=i -> x1
#if PRNG_VARIANT == 0
    uk[i] = o0 >> 9;
#elif PRNG_VARIANT == 1
    uk[i] = o1 >> 9;
#else
    uk[i] = (o0 ^ o1) >> 9; // partitionable bit_width==32: bits1 ^ bits2
#endif
  }
#endif
  int idx[NSEG_];
  for (int i = 0; i < NSEG_; ++i) idx[i] = i;
  std::stable_sort(idx, idx + NSEG_, [&](int a, int b) { return uk[a] < uk[b]; });
  for (int k = 0; k < NSEG_; ++k) perm[k] = (unsigned short)idx[k];
}

// ---------------- pass 1: per-block partial column sums (f64, deterministic) ----------------
__global__ __launch_bounds__(256) void k_colsum(const float* __restrict__ img,
                                                double* __restrict__ partial,
                                                int rpb, int rows) {
  const int t = threadIdx.x;
  const int r0 = blockIdx.x * rpb;
  const int r1 = min(r0 + rpb, rows);
  const int w0 = t, w1 = t + 256, w2 = t + 512;
  double a0 = 0.0, a1 = 0.0, a2 = 0.0;
  for (int r = r0; r < r1; ++r) {
    const float* p = img + (size_t)r * W_;
    a0 += p[w0];
    if (w1 < W_) a1 += p[w1];
    if (w2 < W_) a2 += p[w2];
  }
  double* o = partial + (size_t)blockIdx.x * W_;
  o[w0] = a0;
  if (w1 < W_) o[w1] = a1;
  if (w2 < W_) o[w2] = a2;
}

// ---------------- pass 1b: fixed-order tree reduction of partials ----------------
__global__ __launch_bounds__(64) void k_colreduce(const double* __restrict__ partial,
                                                  double* __restrict__ col, int nblk) {
  const int w = blockIdx.x;       // 690 blocks
  const int lane = threadIdx.x;   // one wave
  double s = 0.0;
  for (int b = lane; b < nblk; b += 64) s += partial[(size_t)b * W_ + w];
  for (int off = 32; off >= 1; off >>= 1) s += __shfl_down(s, off);
  if (lane == 0) col[w] = s;
}

// ---------------- pass 2: the whole W=690 mapping pipeline, one block ----------------
__global__ __launch_bounds__(256) void k_map(const double* __restrict__ col,
                                             int* __restrict__ src, PermArg perm) {
  __shared__ double sa[NCUTS_], sb[NCUTS_];   // scan ping-pong
  __shared__ float ex[W_ + 1];                // exclusive prefix sums (f32, like cs)
  __shared__ unsigned char mm[W_];
  __shared__ int hist[W_ + 1];
  __shared__ int cuts[NCUTS_];
  __shared__ int pl[NSEG_], cum[NSEG_], ssrc[W_];
  const int t = threadIdx.x;

  auto scan_incl = [&](int n) { // Hillis-Steele inclusive scan in sa (deterministic)
    double* s = sa; double* d = sb;
    for (int off = 1; off < n; off <<= 1) {
      for (int i = t; i < n; i += 256) d[i] = (i >= off) ? s[i] + s[i - off] : s[i];
      __syncthreads();
      double* tmp = s; s = d; d = tmp;
    }
    if (s != sa) { for (int i = t; i < n; i += 256) sa[i] = s[i]; __syncthreads(); }
  };

  // 1) prefix sums of col (f64 scan ~= exact; cast to f32 like reference cs)
  for (int i = t; i < W_; i += 256) sa[i] = col[i];
  __syncthreads();
  scan_incl(W_);
  for (int i = t; i <= W_; i += 256) ex[i] = (i == 0) ? 0.0f : (float)sa[i - 1];
  __syncthreads();

  // 2) windowed mean >= global mean mask
  const float gmean = ex[W_] / 45219840.0f; // n_bc*W = 65536*690, exact in f32
  for (int w = t; w < W_; w += 256) {
    int e = (w + 4 < W_) ? w + 4 : W_;
    float wsum = ex[e] - ex[w];
    float wmean = wsum / ((float)(e - w) * 65536.0f);
    mm[w] = (wmean >= gmean) ? 1 : 0;
  }
  for (int i = t; i <= W_; i += 256) hist[i] = 0;
  __syncthreads();

  // 3) counting-sort histogram of cut values
  for (int w = t; w < W_; w += 256) {
    bool cur = mm[w] != 0;
    bool prv = (w > 0) && (mm[w - 1] != 0);
    bool nxt = (w < W_ - 1) && (mm[w + 1] != 0);
    int sv = (cur && !prv) ? w : W_;
    int lv = (cur && !nxt) ? w : W_;
    atomicAdd(&hist[sv], 1);
    atomicAdd(&hist[lv], 1);
  }
  if (t == 0) { atomicAdd(&hist[0], 1); atomicAdd(&hist[W_], 1); } // explicit [0, W]
  __syncthreads();

  // 4) inclusive scan of histogram (counts are small ints, exact in f64)
  for (int i = t; i <= W_; i += 256) sa[i] = (double)hist[i];
  __syncthreads();
  scan_incl(W_ + 1);
  for (int i = t; i <= W_; i += 256) hist[i] = (int)(sa[i] + 0.5);
  __syncthreads();

  // 5) emit sorted cuts: cuts[k] = min v with hist_incl[v] > k
  for (int k = t; k < NCUTS_; k += 256) {
    int lo = 0, hi = W_;
    while (lo < hi) { int mid = (lo + hi) >> 1; if (hist[mid] > k) hi = mid; else lo = mid + 1; }
    cuts[k] = lo;
  }
  __syncthreads();

  // 6) permuted lengths + cumulative sum
  for (int k = t; k < NSEG_; k += 256) { int p = perm.p[k]; pl[k] = cuts[p + 1] - cuts[p]; }
  __syncthreads();
  for (int k = t; k < NSEG_; k += 256) sa[k] = (double)pl[k];
  __syncthreads();
  scan_incl(NSEG_);
  for (int k = t; k < NSEG_; k += 256) cum[k] = (int)(sa[k] + 0.5);
  __syncthreads();

  // 7) fill src: segment k occupies [cum[k]-pl[k], cum[k])
  for (int k = t; k < NSEG_; k += 256) {
    int L = pl[k];
    if (L > 0) {
      int base = cum[k] - L;
      int s0 = cuts[perm.p[k]];
      for (int j = 0; j < L; ++j) ssrc[base + j] = s0 + j;
    }
  }
  __syncthreads();
  for (int p = t; p < W_; p += 256) src[p] = ssrc[p];
}

// ---------------- pass 3: gather out[r, p] = img[r, src[p]] ----------------
__global__ __launch_bounds__(256) void k_gather(const float* __restrict__ img,
                                                float* __restrict__ out,
                                                const int* __restrict__ src, int rows) {
  __shared__ int s_src[W_];
  for (int i = threadIdx.x; i < W_; i += 256) s_src[i] = src[i];
  __syncthreads();
  for (int r = blockIdx.x; r < rows; r += gridDim.x) {
    const float* in = img + (size_t)r * W_;
    float* o = out + (size_t)r * W_;
    for (int p = threadIdx.x; p < W_; p += 256) o[p] = in[s_src[p]];
  }
}

extern "C" void kernel_launch(void* const* d_in, const int* in_sizes, int n_in,
                              void* d_out, int out_size, void* d_ws, size_t ws_size,
                              hipStream_t stream) {
  const float* img = (const float*)d_in[0];
  float* out = (float*)d_out;
  const int rows = in_sizes[0] / W_; // 32*2048 = 65536

  // workspace layout: col f64[690] | src i32[690] | partial f64[nblk*690]
  char* ws = (char*)d_ws;
  double* col = (double*)ws;              // 5520 B @ 0
  int* src = (int*)(ws + 5632);           // 2760 B
  double* partial = (double*)(ws + 8704); // nblk * 5520 B
  size_t avail = (ws_size > 8704) ? ws_size - 8704 : 0;
  int nblk = (int)std::min<size_t>(512, avail / (W_ * sizeof(double)));
  if (nblk < 1) nblk = 1;
  const int rpb = (rows + nblk - 1) / nblk;

  PermArg pa;
  compute_perm(pa.p); // host, input-independent, deterministic

  k_colsum<<<nblk, 256, 0, stream>>>(img, partial, rpb, rows);
  k_colreduce<<<W_, 64, 0, stream>>>(partial, col, nblk);
  k_map<<<1, 256, 0, stream>>>(col, src, pa);
  k_gather<<<4096, 256, 0, stream>>>(img, out, src, rows);
}

// Round 5
// 152.480 us; speedup vs baseline: 1.6761x; 1.6761x over previous
//
#include <hip/hip_runtime.h>
#include <algorithm>
#include <cstdint>

// PRNG: partitionable threefry, 32-bit combine = o0 ^ o1  [VERIFIED R4: absmax=0]

constexpr int W_ = 690;
constexpr int NSEG_ = 2 * W_ + 1;   // 1381 segments
constexpr int NCUTS_ = 2 * W_ + 2;  // 1382 cut points
constexpr int TR_ = 8;              // rows per colsum tile (22080 B LDS, 16B-aligned)

struct PermArg { unsigned short p[NSEG_]; }; // 2762 B kernarg, values < 1381

// ---------------- host-side threefry2x32 (exact JAX semantics) ----------------
static inline uint32_t rotl32_(uint32_t x, int d) { return (x << d) | (x >> (32 - d)); }

static void tf2x32(uint32_t k0, uint32_t k1, uint32_t x0, uint32_t x1,
                   uint32_t& o0, uint32_t& o1) {
  const uint32_t ks2 = k0 ^ k1 ^ 0x1BD11BDAu;
  x0 += k0; x1 += k1;
  const int RA[4] = {13, 15, 26, 6}, RB[4] = {17, 29, 16, 24};
#define FOUR_(R) for (int i_ = 0; i_ < 4; ++i_) { x0 += x1; x1 = rotl32_(x1, R[i_]); x1 ^= x0; }
  FOUR_(RA) x0 += k1;  x1 += ks2 + 1u;
  FOUR_(RB) x0 += ks2; x1 += k0 + 2u;
  FOUR_(RA) x0 += k0;  x1 += k1 + 3u;
  FOUR_(RB) x0 += k1;  x1 += ks2 + 4u;
  FOUR_(RA) x0 += ks2; x1 += k0 + 5u;
#undef FOUR_
  o0 = x0; o1 = x1;
}

// perm = argsort(uniform(key(42), (1381,))) — pure function of constants.
static void compute_perm(unsigned short* perm) {
  uint32_t uk[NSEG_];
  for (int i = 0; i < NSEG_; ++i) {
    uint32_t o0, o1;
    tf2x32(0u, 42u, 0u, (uint32_t)i, o0, o1); // u64 count i: hi=0 -> x0, lo=i -> x1
    uk[i] = (o0 ^ o1) >> 9; // partitionable bit_width==32: bits1 ^ bits2
  }
  int idx[NSEG_];
  for (int i = 0; i < NSEG_; ++i) idx[i] = i;
  std::stable_sort(idx, idx + NSEG_, [&](int a, int b) { return uk[a] < uk[b]; });
  for (int k = 0; k < NSEG_; ++k) perm[k] = (unsigned short)idx[k];
}

// ---------------- pass 1: LDS-staged per-block partial column sums (f64, deterministic) ----------------
__global__ __launch_bounds__(256) void k_colsum(const float* __restrict__ img,
                                                double* __restrict__ partial,
                                                int ntiles, int rows) {
  __shared__ float tile[TR_ * W_]; // 22080 B
  const int t = threadIdx.x;
  double a0 = 0.0, a1 = 0.0, a2 = 0.0;
  for (int g = blockIdx.x; g < ntiles; g += gridDim.x) {
    const int r0 = g * TR_;
    const int nr = min(TR_, rows - r0);
    const int nflt = nr * W_;
    const float* base = img + (size_t)r0 * W_;
    if ((nflt & 3) == 0 && ((((uintptr_t)base) & 15) == 0)) {
      const float4* b4 = (const float4*)base;
      float4* t4 = (float4*)tile;
      const int n4 = nflt >> 2; // 1380 for full tile
      for (int i = t; i < n4; i += 256) t4[i] = b4[i];
    } else {
      for (int i = t; i < nflt; i += 256) tile[i] = base[i];
    }
    __syncthreads();
    for (int r = 0; r < nr; ++r) {
      const float* row = tile + r * W_;
      a0 += (double)row[t];
      a1 += (double)row[t + 256];            // t+256 <= 511 < 690 always
      if (t + 512 < W_) a2 += (double)row[t + 512];
    }
    __syncthreads();
  }
  double* o = partial + (size_t)blockIdx.x * W_;
  o[t] = a0;
  o[t + 256] = a1;
  if (t + 512 < W_) o[t + 512] = a2;
}

// ---------------- pass 1b: fixed-order tree reduction of partials ----------------
__global__ __launch_bounds__(64) void k_colreduce(const double* __restrict__ partial,
                                                  double* __restrict__ col, int nblk) {
  const int w = blockIdx.x;       // 690 blocks
  const int lane = threadIdx.x;   // one wave
  double s = 0.0;
  for (int b = lane; b < nblk; b += 64) s += partial[(size_t)b * W_ + w];
  for (int off = 32; off >= 1; off >>= 1) s += __shfl_down(s, off);
  if (lane == 0) col[w] = s;
}

// ---------------- pass 2: the whole W=690 mapping pipeline, one block ----------------
__global__ __launch_bounds__(256) void k_map(const double* __restrict__ col,
                                             int* __restrict__ src, PermArg perm) {
  __shared__ double sa[NCUTS_], sb[NCUTS_];   // scan ping-pong
  __shared__ float ex[W_ + 1];                // exclusive prefix sums (f32, like cs)
  __shared__ unsigned char mm[W_];
  __shared__ int hist[W_ + 1];
  __shared__ int cuts[NCUTS_];
  __shared__ int pl[NSEG_], cum[NSEG_], ssrc[W_];
  const int t = threadIdx.x;

  auto scan_incl = [&](int n) { // Hillis-Steele inclusive scan in sa (deterministic)
    double* s = sa; double* d = sb;
    for (int off = 1; off < n; off <<= 1) {
      for (int i = t; i < n; i += 256) d[i] = (i >= off) ? s[i] + s[i - off] : s[i];
      __syncthreads();
      double* tmp = s; s = d; d = tmp;
    }
    if (s != sa) { for (int i = t; i < n; i += 256) sa[i] = s[i]; __syncthreads(); }
  };

  // 1) prefix sums of col (f64 scan ~= exact; cast to f32 like reference cs)
  for (int i = t; i < W_; i += 256) sa[i] = col[i];
  __syncthreads();
  scan_incl(W_);
  for (int i = t; i <= W_; i += 256) ex[i] = (i == 0) ? 0.0f : (float)sa[i - 1];
  __syncthreads();

  // 2) windowed mean >= global mean mask
  const float gmean = ex[W_] / 45219840.0f; // n_bc*W = 65536*690, exact in f32
  for (int w = t; w < W_; w += 256) {
    int e = (w + 4 < W_) ? w + 4 : W_;
    float wsum = ex[e] - ex[w];
    float wmean = wsum / ((float)(e - w) * 65536.0f);
    mm[w] = (wmean >= gmean) ? 1 : 0;
  }
  for (int i = t; i <= W_; i += 256) hist[i] = 0;
  __syncthreads();

  // 3) counting-sort histogram of cut values
  for (int w = t; w < W_; w += 256) {
    bool cur = mm[w] != 0;
    bool prv = (w > 0) && (mm[w - 1] != 0);
    bool nxt = (w < W_ - 1) && (mm[w + 1] != 0);
    int sv = (cur && !prv) ? w : W_;
    int lv = (cur && !nxt) ? w : W_;
    atomicAdd(&hist[sv], 1);
    atomicAdd(&hist[lv], 1);
  }
  if (t == 0) { atomicAdd(&hist[0], 1); atomicAdd(&hist[W_], 1); } // explicit [0, W]
  __syncthreads();

  // 4) inclusive scan of histogram (counts are small ints, exact in f64)
  for (int i = t; i <= W_; i += 256) sa[i] = (double)hist[i];
  __syncthreads();
  scan_incl(W_ + 1);
  for (int i = t; i <= W_; i += 256) hist[i] = (int)(sa[i] + 0.5);
  __syncthreads();

  // 5) emit sorted cuts: cuts[k] = min v with hist_incl[v] > k
  for (int k = t; k < NCUTS_; k += 256) {
    int lo = 0, hi = W_;
    while (lo < hi) { int mid = (lo + hi) >> 1; if (hist[mid] > k) hi = mid; else lo = mid + 1; }
    cuts[k] = lo;
  }
  __syncthreads();

  // 6) permuted lengths + cumulative sum
  for (int k = t; k < NSEG_; k += 256) { int p = perm.p[k]; pl[k] = cuts[p + 1] - cuts[p]; }
  __syncthreads();
  for (int k = t; k < NSEG_; k += 256) sa[k] = (double)pl[k];
  __syncthreads();
  scan_incl(NSEG_);
  for (int k = t; k < NSEG_; k += 256) cum[k] = (int)(sa[k] + 0.5);
  __syncthreads();

  // 7) fill src: segment k occupies [cum[k]-pl[k], cum[k])
  for (int k = t; k < NSEG_; k += 256) {
    int L = pl[k];
    if (L > 0) {
      int base = cum[k] - L;
      int s0 = cuts[perm.p[k]];
      for (int j = 0; j < L; ++j) ssrc[base + j] = s0 + j;
    }
  }
  __syncthreads();
  for (int p = t; p < W_; p += 256) src[p] = ssrc[p];
}

// ---------------- pass 3: gather, row-pairs with float4 stores ----------------
// out[r, p] = img[r, src[p]]; a row-pair is 1380 floats = 345 aligned float4.
__global__ __launch_bounds__(256) void k_gather(const float* __restrict__ img,
                                                float* __restrict__ out,
                                                const int* __restrict__ src,
                                                int npairs, int rows) {
  __shared__ int s_src[2 * W_]; // row-resolved source index for pair-offset p
  for (int i = threadIdx.x; i < W_; i += 256) {
    int s = src[i];
    s_src[i] = s;
    s_src[i + W_] = s + W_;
  }
  __syncthreads();
  for (int pr = blockIdx.x; pr < npairs; pr += gridDim.x) {
    const float* in = img + (size_t)pr * (2 * W_);
    float4* o4 = (float4*)(out + (size_t)pr * (2 * W_)); // 5520B*pr -> 16B aligned
    for (int j = threadIdx.x; j < (2 * W_) / 4; j += 256) { // 345 float4
      const int f = 4 * j;
      float4 v;
      v.x = in[s_src[f]];
      v.y = in[s_src[f + 1]];
      v.z = in[s_src[f + 2]];
      v.w = in[s_src[f + 3]];
      o4[j] = v;
    }
  }
  // odd-row tail (not hit for rows=65536, kept for generality)
  if (rows & 1) {
    const int r = rows - 1;
    if (blockIdx.x == 0) {
      const float* in = img + (size_t)r * W_;
      float* o = out + (size_t)r * W_;
      for (int p = threadIdx.x; p < W_; p += 256) o[p] = in[s_src[p]];
    }
  }
}

extern "C" void kernel_launch(void* const* d_in, const int* in_sizes, int n_in,
                              void* d_out, int out_size, void* d_ws, size_t ws_size,
                              hipStream_t stream) {
  const float* img = (const float*)d_in[0];
  float* out = (float*)d_out;
  const int rows = in_sizes[0] / W_; // 32*2048 = 65536

  // workspace layout: col f64[690] | src i32[690] | partial f64[nblk*690]
  char* ws = (char*)d_ws;
  double* col = (double*)ws;              // 5520 B @ 0
  int* src = (int*)(ws + 5632);           // 2760 B
  double* partial = (double*)(ws + 8704); // nblk * 5520 B
  size_t avail = (ws_size > 8704) ? ws_size - 8704 : 0;
  int nblk = (int)std::min<size_t>(1024, avail / (W_ * sizeof(double)));
  if (nblk < 1) nblk = 1;
  const int ntiles = (rows + TR_ - 1) / TR_;

  PermArg pa;
  compute_perm(pa.p); // host, input-independent, deterministic

  k_colsum<<<nblk, 256, 0, stream>>>(img, partial, ntiles, rows);
  k_colreduce<<<W_, 64, 0, stream>>>(partial, col, nblk);
  k_map<<<1, 256, 0, stream>>>(col, src, pa);
  k_gather<<<8192, 256, 0, stream>>>(img, out, src, rows / 2, rows);
}

// Round 6
// 135.757 us; speedup vs baseline: 1.8825x; 1.1232x over previous
//
#include <hip/hip_runtime.h>
#include <algorithm>
#include <cstdint>

// PRNG: partitionable threefry, 32-bit combine = o0 ^ o1  [VERIFIED R4: absmax=0]

constexpr int W_ = 690;
constexpr int NSEG_ = 2 * W_ + 1;   // 1381 segments
constexpr int NCUTS_ = 2 * W_ + 2;  // 1382 cut points
constexpr int TR4_ = 4;             // rows per tile (colsum buffer / gather tile)
constexpr int TFLT_ = TR4_ * W_;    // 2760 floats = 11040 B (16B-aligned tiles)
constexpr int TF4_ = TFLT_ / 4;     // 690 float4 per tile

struct PermArg { unsigned short p[NSEG_]; }; // 2762 B kernarg, values < 1381

// ---------------- host-side threefry2x32 (exact JAX semantics) ----------------
static inline uint32_t rotl32_(uint32_t x, int d) { return (x << d) | (x >> (32 - d)); }

static void tf2x32(uint32_t k0, uint32_t k1, uint32_t x0, uint32_t x1,
                   uint32_t& o0, uint32_t& o1) {
  const uint32_t ks2 = k0 ^ k1 ^ 0x1BD11BDAu;
  x0 += k0; x1 += k1;
  const int RA[4] = {13, 15, 26, 6}, RB[4] = {17, 29, 16, 24};
#define FOUR_(R) for (int i_ = 0; i_ < 4; ++i_) { x0 += x1; x1 = rotl32_(x1, R[i_]); x1 ^= x0; }
  FOUR_(RA) x0 += k1;  x1 += ks2 + 1u;
  FOUR_(RB) x0 += ks2; x1 += k0 + 2u;
  FOUR_(RA) x0 += k0;  x1 += k1 + 3u;
  FOUR_(RB) x0 += k1;  x1 += ks2 + 4u;
  FOUR_(RA) x0 += ks2; x1 += k0 + 5u;
#undef FOUR_
  o0 = x0; o1 = x1;
}

// perm = argsort(uniform(key(42), (1381,))) — pure function of constants.
static void compute_perm(unsigned short* perm) {
  uint32_t uk[NSEG_];
  for (int i = 0; i < NSEG_; ++i) {
    uint32_t o0, o1;
    tf2x32(0u, 42u, 0u, (uint32_t)i, o0, o1); // u64 count i: hi=0 -> x0, lo=i -> x1
    uk[i] = (o0 ^ o1) >> 9; // partitionable bit_width==32: bits1 ^ bits2
  }
  int idx[NSEG_];
  for (int i = 0; i < NSEG_; ++i) idx[i] = i;
  std::stable_sort(idx, idx + NSEG_, [&](int a, int b) { return uk[a] < uk[b]; });
  for (int k = 0; k < NSEG_; ++k) perm[k] = (unsigned short)idx[k];
}

// ---------------- pass 1: double-buffered LDS-staged column sums (f64, deterministic) ----------------
__global__ __launch_bounds__(256) void k_colsum(const float* __restrict__ img,
                                                double* __restrict__ partial,
                                                int ntiles, int rows) {
  __shared__ float buf[2][TFLT_]; // 2 x 11040 B
  const int t = threadIdx.x;
  double a0 = 0.0, a1 = 0.0, a2 = 0.0;

  auto stage = [&](float* bp, int g) {
    const int nr = min(TR4_, rows - g * TR4_);
    if (nr == TR4_) {
      const float4* b4 = (const float4*)(img + (size_t)g * TFLT_); // 11040B*g: 16B aligned
      float4* t4 = (float4*)bp;
      for (int i = t; i < TF4_; i += 256) t4[i] = b4[i];
    } else {
      const int nflt = nr * W_;
      const float* b = img + (size_t)g * TFLT_;
      for (int i = t; i < nflt; i += 256) bp[i] = b[i];
    }
  };

  int g = blockIdx.x;
  int phase = 0;
  if (g < ntiles) stage(buf[0], g);
  for (; g < ntiles; g += gridDim.x) {
    __syncthreads(); // buf[phase] staged; prev accumulate of buf[phase^1] done
    const int gn = g + gridDim.x;
    if (gn < ntiles) stage(buf[phase ^ 1], gn); // prefetch next while we accumulate
    const int nr = min(TR4_, rows - g * TR4_);
    const float* bp = buf[phase];
    for (int r = 0; r < nr; ++r) {
      const float* row = bp + r * W_;
      a0 += (double)row[t];
      a1 += (double)row[t + 256];          // t+256 <= 511 < 690 always
      if (t + 512 < W_) a2 += (double)row[t + 512];
    }
    phase ^= 1;
  }
  double* o = partial + (size_t)blockIdx.x * W_;
  o[t] = a0;
  o[t + 256] = a1;
  if (t + 512 < W_) o[t + 512] = a2;
}

// ---------------- pass 1b: fixed-order tree reduction of partials ----------------
__global__ __launch_bounds__(64) void k_colreduce(const double* __restrict__ partial,
                                                  double* __restrict__ col, int nblk) {
  const int w = blockIdx.x;       // 690 blocks
  const int lane = threadIdx.x;   // one wave
  double s = 0.0;
  for (int b = lane; b < nblk; b += 64) s += partial[(size_t)b * W_ + w];
  for (int off = 32; off >= 1; off >>= 1) s += __shfl_down(s, off);
  if (lane == 0) col[w] = s;
}

// ---------------- pass 2: the whole W=690 mapping pipeline, one block ----------------
__global__ __launch_bounds__(256) void k_map(const double* __restrict__ col,
                                             int* __restrict__ src, PermArg perm) {
  __shared__ double sa[NCUTS_], sb[NCUTS_];   // scan ping-pong
  __shared__ float ex[W_ + 1];                // exclusive prefix sums (f32, like cs)
  __shared__ unsigned char mm[W_];
  __shared__ int hist[W_ + 1];
  __shared__ int cuts[NCUTS_];
  __shared__ int pl[NSEG_], cum[NSEG_], ssrc[W_];
  const int t = threadIdx.x;

  auto scan_incl = [&](int n) { // Hillis-Steele inclusive scan in sa (deterministic)
    double* s = sa; double* d = sb;
    for (int off = 1; off < n; off <<= 1) {
      for (int i = t; i < n; i += 256) d[i] = (i >= off) ? s[i] + s[i - off] : s[i];
      __syncthreads();
      double* tmp = s; s = d; d = tmp;
    }
    if (s != sa) { for (int i = t; i < n; i += 256) sa[i] = s[i]; __syncthreads(); }
  };

  // 1) prefix sums of col (f64 scan ~= exact; cast to f32 like reference cs)
  for (int i = t; i < W_; i += 256) sa[i] = col[i];
  __syncthreads();
  scan_incl(W_);
  for (int i = t; i <= W_; i += 256) ex[i] = (i == 0) ? 0.0f : (float)sa[i - 1];
  __syncthreads();

  // 2) windowed mean >= global mean mask
  const float gmean = ex[W_] / 45219840.0f; // n_bc*W = 65536*690, exact in f32
  for (int w = t; w < W_; w += 256) {
    int e = (w + 4 < W_) ? w + 4 : W_;
    float wsum = ex[e] - ex[w];
    float wmean = wsum / ((float)(e - w) * 65536.0f);
    mm[w] = (wmean >= gmean) ? 1 : 0;
  }
  for (int i = t; i <= W_; i += 256) hist[i] = 0;
  __syncthreads();

  // 3) counting-sort histogram of cut values
  for (int w = t; w < W_; w += 256) {
    bool cur = mm[w] != 0;
    bool prv = (w > 0) && (mm[w - 1] != 0);
    bool nxt = (w < W_ - 1) && (mm[w + 1] != 0);
    int sv = (cur && !prv) ? w : W_;
    int lv = (cur && !nxt) ? w : W_;
    atomicAdd(&hist[sv], 1);
    atomicAdd(&hist[lv], 1);
  }
  if (t == 0) { atomicAdd(&hist[0], 1); atomicAdd(&hist[W_], 1); } // explicit [0, W]
  __syncthreads();

  // 4) inclusive scan of histogram (counts are small ints, exact in f64)
  for (int i = t; i <= W_; i += 256) sa[i] = (double)hist[i];
  __syncthreads();
  scan_incl(W_ + 1);
  for (int i = t; i <= W_; i += 256) hist[i] = (int)(sa[i] + 0.5);
  __syncthreads();

  // 5) emit sorted cuts: cuts[k] = min v with hist_incl[v] > k
  for (int k = t; k < NCUTS_; k += 256) {
    int lo = 0, hi = W_;
    while (lo < hi) { int mid = (lo + hi) >> 1; if (hist[mid] > k) hi = mid; else lo = mid + 1; }
    cuts[k] = lo;
  }
  __syncthreads();

  // 6) permuted lengths + cumulative sum
  for (int k = t; k < NSEG_; k += 256) { int p = perm.p[k]; pl[k] = cuts[p + 1] - cuts[p]; }
  __syncthreads();
  for (int k = t; k < NSEG_; k += 256) sa[k] = (double)pl[k];
  __syncthreads();
  scan_incl(NSEG_);
  for (int k = t; k < NSEG_; k += 256) cum[k] = (int)(sa[k] + 0.5);
  __syncthreads();

  // 7) fill src: segment k occupies [cum[k]-pl[k], cum[k])
  for (int k = t; k < NSEG_; k += 256) {
    int L = pl[k];
    if (L > 0) {
      int base = cum[k] - L;
      int s0 = cuts[perm.p[k]];
      for (int j = 0; j < L; ++j) ssrc[base + j] = s0 + j;
    }
  }
  __syncthreads();
  for (int p = t; p < W_; p += 256) src[p] = ssrc[p];
}

// ---------------- pass 3: LDS-staged gather, 4 rows per tile ----------------
// Stage 4 rows coalesced (690 float4), scatter-read from LDS, coalesced float4 stores.
__global__ __launch_bounds__(256) void k_gather(const float* __restrict__ img,
                                                float* __restrict__ out,
                                                const int* __restrict__ src,
                                                int ntile4, int rows) {
  __shared__ float buf[TFLT_];  // 11040 B (4 rows)
  __shared__ int ss[2 * W_];    // row-resolved source idx for 2-row window (1380)
  const int t = threadIdx.x;
  for (int i = t; i < W_; i += 256) {
    int s = src[i];
    ss[i] = s;
    ss[i + W_] = s + W_;
  }
  __syncthreads();
  for (int g = blockIdx.x; g < ntile4; g += gridDim.x) {
    const float4* in4 = (const float4*)(img + (size_t)g * TFLT_); // 16B aligned
    float4* b4 = (float4*)buf;
    for (int i = t; i < TF4_; i += 256) b4[i] = in4[i];
    __syncthreads();
    float4* o4 = (float4*)(out + (size_t)g * TFLT_);
    for (int q = t; q < TF4_; q += 256) {
      const int f = 4 * q;                       // quads never cross the 1380 boundary
      const int hb = (f >= 2 * W_) ? 2 * W_ : 0; // 2-row half base
      const float* hbuf = buf + hb;
      const int off = f - hb;
      float4 v;
      v.x = hbuf[ss[off]];
      v.y = hbuf[ss[off + 1]];
      v.z = hbuf[ss[off + 2]];
      v.w = hbuf[ss[off + 3]];
      o4[q] = v;
    }
    __syncthreads(); // buf reused next iteration
  }
  // tail rows (rows % 4), scalar — not hit for rows=65536
  const int tail0 = ntile4 * TR4_;
  if (tail0 < rows && blockIdx.x == 0) {
    for (int r = tail0; r < rows; ++r) {
      const float* in = img + (size_t)r * W_;
      float* o = out + (size_t)r * W_;
      for (int p = t; p < W_; p += 256) o[p] = in[ss[p]];
    }
  }
}

extern "C" void kernel_launch(void* const* d_in, const int* in_sizes, int n_in,
                              void* d_out, int out_size, void* d_ws, size_t ws_size,
                              hipStream_t stream) {
  const float* img = (const float*)d_in[0];
  float* out = (float*)d_out;
  const int rows = in_sizes[0] / W_; // 32*2048 = 65536

  // workspace layout: col f64[690] | src i32[690] | partial f64[nblk*690]
  char* ws = (char*)d_ws;
  double* col = (double*)ws;              // 5520 B @ 0
  int* src = (int*)(ws + 5632);           // 2760 B
  double* partial = (double*)(ws + 8704); // nblk * 5520 B
  size_t avail = (ws_size > 8704) ? ws_size - 8704 : 0;
  int nblk = (int)std::min<size_t>(1792, avail / (W_ * sizeof(double)));
  if (nblk < 1) nblk = 1;
  const int ntiles = (rows + TR4_ - 1) / TR4_;
  const int ntile4 = rows / TR4_;

  PermArg pa;
  compute_perm(pa.p); // host, input-independent, deterministic

  k_colsum<<<nblk, 256, 0, stream>>>(img, partial, ntiles, rows);
  k_colreduce<<<W_, 64, 0, stream>>>(partial, col, nblk);
  k_map<<<1, 256, 0, stream>>>(col, src, pa);
  k_gather<<<2048, 256, 0, stream>>>(img, out, src, ntile4, rows);
}

// Round 7
// 116.362 us; speedup vs baseline: 2.1963x; 1.1667x over previous
//
#include <hip/hip_runtime.h>
#include <algorithm>
#include <cstdint>

// PRNG: partitionable threefry, 32-bit combine = o0 ^ o1  [VERIFIED R4: absmax=0]

constexpr int W_ = 690;
constexpr int NSEG_ = 2 * W_ + 1;   // 1381 segments
constexpr int NCUTS_ = 2 * W_ + 2;  // 1382 cut points
constexpr int TR4_ = 4;             // rows per tile (colsum buffer / gather tile)
constexpr int TFLT_ = TR4_ * W_;    // 2760 floats = 11040 B (16B-aligned tiles)
constexpr int TF4_ = TFLT_ / 4;     // 690 float4 per tile

typedef float v4f_ __attribute__((ext_vector_type(4)));

struct PermArg { unsigned short p[NSEG_]; }; // 2762 B kernarg, values < 1381

// ---------------- host-side threefry2x32 (exact JAX semantics) ----------------
static inline uint32_t rotl32_(uint32_t x, int d) { return (x << d) | (x >> (32 - d)); }

static void tf2x32(uint32_t k0, uint32_t k1, uint32_t x0, uint32_t x1,
                   uint32_t& o0, uint32_t& o1) {
  const uint32_t ks2 = k0 ^ k1 ^ 0x1BD11BDAu;
  x0 += k0; x1 += k1;
  const int RA[4] = {13, 15, 26, 6}, RB[4] = {17, 29, 16, 24};
#define FOUR_(R) for (int i_ = 0; i_ < 4; ++i_) { x0 += x1; x1 = rotl32_(x1, R[i_]); x1 ^= x0; }
  FOUR_(RA) x0 += k1;  x1 += ks2 + 1u;
  FOUR_(RB) x0 += ks2; x1 += k0 + 2u;
  FOUR_(RA) x0 += k0;  x1 += k1 + 3u;
  FOUR_(RB) x0 += k1;  x1 += ks2 + 4u;
  FOUR_(RA) x0 += ks2; x1 += k0 + 5u;
#undef FOUR_
  o0 = x0; o1 = x1;
}

// perm = argsort(uniform(key(42), (1381,))) — pure function of constants.
static void compute_perm(unsigned short* perm) {
  uint32_t uk[NSEG_];
  for (int i = 0; i < NSEG_; ++i) {
    uint32_t o0, o1;
    tf2x32(0u, 42u, 0u, (uint32_t)i, o0, o1); // u64 count i: hi=0 -> x0, lo=i -> x1
    uk[i] = (o0 ^ o1) >> 9; // partitionable bit_width==32: bits1 ^ bits2
  }
  int idx[NSEG_];
  for (int i = 0; i < NSEG_; ++i) idx[i] = i;
  std::stable_sort(idx, idx + NSEG_, [&](int a, int b) { return uk[a] < uk[b]; });
  for (int k = 0; k < NSEG_; ++k) perm[k] = (unsigned short)idx[k];
}

// ---------------- pass 1: double-buffered LDS-staged column sums (f64, deterministic) ----------------
__global__ __launch_bounds__(256) void k_colsum(const float* __restrict__ img,
                                                double* __restrict__ partial,
                                                int ntiles, int rows) {
  __shared__ float buf[2][TFLT_]; // 2 x 11040 B
  const int t = threadIdx.x;
  double a0 = 0.0, a1 = 0.0, a2 = 0.0;

  auto stage = [&](float* bp, int g) {
    const int nr = min(TR4_, rows - g * TR4_);
    if (nr == TR4_) {
      const v4f_* b4 = (const v4f_*)(img + (size_t)g * TFLT_); // 11040B*g: 16B aligned
      v4f_* t4 = (v4f_*)bp;
      for (int i = t; i < TF4_; i += 256) t4[i] = b4[i];
    } else {
      const int nflt = nr * W_;
      const float* b = img + (size_t)g * TFLT_;
      for (int i = t; i < nflt; i += 256) bp[i] = b[i];
    }
  };

  int g = blockIdx.x;
  int phase = 0;
  if (g < ntiles) stage(buf[0], g);
  for (; g < ntiles; g += gridDim.x) {
    __syncthreads(); // buf[phase] staged; prev accumulate of buf[phase^1] done
    const int gn = g + gridDim.x;
    if (gn < ntiles) stage(buf[phase ^ 1], gn); // prefetch next while we accumulate
    const int nr = min(TR4_, rows - g * TR4_);
    const float* bp = buf[phase];
    for (int r = 0; r < nr; ++r) {
      const float* row = bp + r * W_;
      a0 += (double)row[t];
      a1 += (double)row[t + 256];          // t+256 <= 511 < 690 always
      if (t + 512 < W_) a2 += (double)row[t + 512];
    }
    phase ^= 1;
  }
  double* o = partial + (size_t)blockIdx.x * W_;
  o[t] = a0;
  o[t + 256] = a1;
  if (t + 512 < W_) o[t + 512] = a2;
}

// ---------------- pass 1b: fixed-order tree reduction of partials ----------------
__global__ __launch_bounds__(64) void k_colreduce(const double* __restrict__ partial,
                                                  double* __restrict__ col, int nblk) {
  const int w = blockIdx.x;       // 690 blocks
  const int lane = threadIdx.x;   // one wave
  double s = 0.0;
  for (int b = lane; b < nblk; b += 64) s += partial[(size_t)b * W_ + w];
  for (int off = 32; off >= 1; off >>= 1) s += __shfl_down(s, off);
  if (lane == 0) col[w] = s;
}

// ---------------- hierarchical inclusive scan: 2 barriers, deterministic ----------------
// sa[0..N) in LDS -> inclusive prefix. Per-thread serial chunk (registers, unrolled),
// wave shuffle-scan of chunk totals, wave-offset add-back.
template <int N>
__device__ inline void scan_fast(double* sa, int t, double* wtmp) {
  constexpr int C = (N + 255) / 256;
  double loc[C];
  const int base = t * C;
  double run = 0.0;
#pragma unroll
  for (int j = 0; j < C; ++j) {
    const int i = base + j;
    const double v = (i < N) ? sa[i] : 0.0;
    run += v;
    loc[j] = run;
  }
  const int lane = t & 63, wid = t >> 6;
  double x = run;
#pragma unroll
  for (int off = 1; off < 64; off <<= 1) {
    const double y = __shfl_up(x, off);
    if (lane >= off) x += y;
  }
  if (lane == 63) wtmp[wid] = x;
  __syncthreads(); // all sa reads done; wave totals visible
  double excl = x - run; // exclusive prefix of this thread within its wave
  for (int k = 0; k < wid; ++k) excl += wtmp[k];
#pragma unroll
  for (int j = 0; j < C; ++j) {
    const int i = base + j;
    if (i < N) sa[i] = excl + loc[j];
  }
  __syncthreads();
}

// ---------------- pass 2: the whole W=690 mapping pipeline, one block ----------------
__global__ __launch_bounds__(256) void k_map(const double* __restrict__ col,
                                             int* __restrict__ src, PermArg perm) {
  __shared__ double sa[NCUTS_];
  __shared__ double wtmp[4];
  __shared__ float ex[W_ + 1];                // exclusive prefix sums (f32, like cs)
  __shared__ unsigned char mm[W_];
  __shared__ int hist[W_ + 1];
  __shared__ int cuts[NCUTS_];
  __shared__ int pl[NSEG_], cum[NSEG_], ssrc[W_];
  const int t = threadIdx.x;

  // 1) prefix sums of col (f64 scan ~= exact; cast to f32 like reference cs)
  for (int i = t; i < W_; i += 256) sa[i] = col[i];
  __syncthreads();
  scan_fast<W_>(sa, t, wtmp);
  for (int i = t; i <= W_; i += 256) ex[i] = (i == 0) ? 0.0f : (float)sa[i - 1];
  __syncthreads();

  // 2) windowed mean >= global mean mask
  const float gmean = ex[W_] / 45219840.0f; // n_bc*W = 65536*690, exact in f32
  for (int w = t; w < W_; w += 256) {
    int e = (w + 4 < W_) ? w + 4 : W_;
    float wsum = ex[e] - ex[w];
    float wmean = wsum / ((float)(e - w) * 65536.0f);
    mm[w] = (wmean >= gmean) ? 1 : 0;
  }
  for (int i = t; i <= W_; i += 256) hist[i] = 0;
  __syncthreads();

  // 3) counting-sort histogram of cut values
  for (int w = t; w < W_; w += 256) {
    bool cur = mm[w] != 0;
    bool prv = (w > 0) && (mm[w - 1] != 0);
    bool nxt = (w < W_ - 1) && (mm[w + 1] != 0);
    int sv = (cur && !prv) ? w : W_;
    int lv = (cur && !nxt) ? w : W_;
    atomicAdd(&hist[sv], 1);
    atomicAdd(&hist[lv], 1);
  }
  if (t == 0) { atomicAdd(&hist[0], 1); atomicAdd(&hist[W_], 1); } // explicit [0, W]
  __syncthreads();

  // 4) inclusive scan of histogram (counts are small ints, exact in f64)
  for (int i = t; i <= W_; i += 256) sa[i] = (double)hist[i];
  __syncthreads();
  scan_fast<W_ + 1>(sa, t, wtmp);
  for (int i = t; i <= W_; i += 256) hist[i] = (int)(sa[i] + 0.5);
  __syncthreads();

  // 5) emit sorted cuts: cuts[k] = min v with hist_incl[v] > k
  for (int k = t; k < NCUTS_; k += 256) {
    int lo = 0, hi = W_;
    while (lo < hi) { int mid = (lo + hi) >> 1; if (hist[mid] > k) hi = mid; else lo = mid + 1; }
    cuts[k] = lo;
  }
  __syncthreads();

  // 6) permuted lengths + cumulative sum
  for (int k = t; k < NSEG_; k += 256) { int p = perm.p[k]; pl[k] = cuts[p + 1] - cuts[p]; }
  __syncthreads();
  for (int k = t; k < NSEG_; k += 256) sa[k] = (double)pl[k];
  __syncthreads();
  scan_fast<NSEG_>(sa, t, wtmp);
  for (int k = t; k < NSEG_; k += 256) cum[k] = (int)(sa[k] + 0.5);
  __syncthreads();

  // 7) fill src: segment k occupies [cum[k]-pl[k], cum[k])
  for (int k = t; k < NSEG_; k += 256) {
    int L = pl[k];
    if (L > 0) {
      int base = cum[k] - L;
      int s0 = cuts[perm.p[k]];
      for (int j = 0; j < L; ++j) ssrc[base + j] = s0 + j;
    }
  }
  __syncthreads();
  for (int p = t; p < W_; p += 256) src[p] = ssrc[p];
}

// ---------------- pass 3: double-buffered LDS-staged gather ----------------
// Stage 4 rows coalesced, scatter-read from LDS, nontemporal float4 stores
// (keep img resident in L3 for the re-read; out is never re-read).
__global__ __launch_bounds__(256) void k_gather(const float* __restrict__ img,
                                                float* __restrict__ out,
                                                const int* __restrict__ src,
                                                int ntile4, int rows) {
  __shared__ float buf[2][TFLT_]; // 2 x 11040 B
  __shared__ int ss[2 * W_];      // row-resolved source idx for 2-row window (1380)
  const int t = threadIdx.x;
  for (int i = t; i < W_; i += 256) {
    int s = src[i];
    ss[i] = s;
    ss[i + W_] = s + W_;
  }

  auto stage = [&](float* bp, int g) {
    const v4f_* in4 = (const v4f_*)(img + (size_t)g * TFLT_); // 16B aligned
    v4f_* t4 = (v4f_*)bp;
    for (int i = t; i < TF4_; i += 256) t4[i] = in4[i];
  };

  int g = blockIdx.x;
  int phase = 0;
  if (g < ntile4) stage(buf[0], g);
  for (; g < ntile4; g += gridDim.x) {
    __syncthreads(); // buf[phase] staged; prior reads of buf[phase^1] done
    const int gn = g + gridDim.x;
    if (gn < ntile4) stage(buf[phase ^ 1], gn); // prefetch next tile
    const float* bp = buf[phase];
    v4f_* o4 = (v4f_*)(out + (size_t)g * TFLT_);
    for (int q = t; q < TF4_; q += 256) {
      const int f = 4 * q;                       // quads never cross the 1380 boundary
      const int hb = (f >= 2 * W_) ? 2 * W_ : 0; // 2-row half base
      const float* hbuf = bp + hb;
      const int off = f - hb;
      v4f_ v;
      v[0] = hbuf[ss[off]];
      v[1] = hbuf[ss[off + 1]];
      v[2] = hbuf[ss[off + 2]];
      v[3] = hbuf[ss[off + 3]];
      __builtin_nontemporal_store(v, &o4[q]);
    }
    phase ^= 1;
  }
  // tail rows (rows % 4), scalar — not hit for rows=65536
  const int tail0 = ntile4 * TR4_;
  if (tail0 < rows && blockIdx.x == 0) {
    __syncthreads();
    for (int r = tail0; r < rows; ++r) {
      const float* in = img + (size_t)r * W_;
      float* o = out + (size_t)r * W_;
      for (int p = t; p < W_; p += 256) o[p] = in[ss[p]];
    }
  }
}

extern "C" void kernel_launch(void* const* d_in, const int* in_sizes, int n_in,
                              void* d_out, int out_size, void* d_ws, size_t ws_size,
                              hipStream_t stream) {
  const float* img = (const float*)d_in[0];
  float* out = (float*)d_out;
  const int rows = in_sizes[0] / W_; // 32*2048 = 65536

  // workspace layout: col f64[690] | src i32[690] | partial f64[nblk*690]
  char* ws = (char*)d_ws;
  double* col = (double*)ws;              // 5520 B @ 0
  int* src = (int*)(ws + 5632);           // 2760 B
  double* partial = (double*)(ws + 8704); // nblk * 5520 B
  size_t avail = (ws_size > 8704) ? ws_size - 8704 : 0;
  int nblk = (int)std::min<size_t>(1792, avail / (W_ * sizeof(double)));
  if (nblk < 1) nblk = 1;
  const int ntiles = (rows + TR4_ - 1) / TR4_;
  const int ntile4 = rows / TR4_;

  PermArg pa;
  compute_perm(pa.p); // host, input-independent, deterministic

  k_colsum<<<nblk, 256, 0, stream>>>(img, partial, ntiles, rows);
  k_colreduce<<<W_, 64, 0, stream>>>(partial, col, nblk);
  k_map<<<1, 256, 0, stream>>>(col, src, pa);
  k_gather<<<1280, 256, 0, stream>>>(img, out, src, ntile4, rows);
}